// Round 6
// baseline (664.734 us; speedup 1.0000x reference)
//
#include <hip/hip_runtime.h>
#include <hip/hip_bf16.h>

#define N_NODES 100000
#define N_EDGES 3200000
#define NB 391                         // ceil(100000/256) buckets of 256 nodes
#define NBP 400                        // padded
#define CAP 9216                       // fixed bucket capacity: mean 8184 + 11.4 sigma
#define SPB 2049                       // seg_ptr entries per bucket
#define NTILES 6250                    // 100000 / 16

typedef __attribute__((ext_vector_type(8))) short short8;
typedef __attribute__((ext_vector_type(4))) float floatx4;

__device__ __forceinline__ float bf2f(unsigned short u) {
    unsigned int x = ((unsigned int)u) << 16;
    return __builtin_bit_cast(float, x);
}
__device__ __forceinline__ unsigned short f2bf(float f) {
    unsigned int u = __builtin_bit_cast(unsigned int, f);
    unsigned int r = (u + 0x7FFFu + ((u >> 16) & 1u)) >> 16;
    return (unsigned short)r;
}

// ============ fixed-capacity bucketed sort by segment (dst*8+t) ============

__global__ __launch_bounds__(512) void k_init(int* __restrict__ cursor) {
    int tid = threadIdx.x;
    if (tid < NB) cursor[tid] = tid * CAP;
}

__global__ __launch_bounds__(1024) void k_bscatter(const int* __restrict__ ei,
                                                   const int* __restrict__ ti,
                                                   int* __restrict__ cursor,
                                                   unsigned int* __restrict__ words) {
    __shared__ int h[NBP];
    __shared__ int bb[NBP];
    __shared__ int lc[NBP];
    int tid = threadIdx.x;
    if (tid < NBP) { h[tid] = 0; lc[tid] = 0; }
    __syncthreads();
    int base = blockIdx.x * 8192;
#pragma unroll
    for (int i = 0; i < 8; ++i) {
        int e = base + i * 1024 + tid;
        if (e < N_EDGES) atomicAdd(&h[ei[N_EDGES + e] >> 8], 1);
    }
    __syncthreads();
    if (tid < NB) {
        int c = h[tid];
        bb[tid] = c ? atomicAdd(&cursor[tid], c) : 0;
    }
    __syncthreads();
#pragma unroll
    for (int i = 0; i < 8; ++i) {
        int e = base + i * 1024 + tid;
        if (e < N_EDGES) {
            int dst = ei[N_EDGES + e];
            int b = dst >> 8;
            int ls = ((dst & 255) << 3) | ti[e];
            int pos = bb[b] + atomicAdd(&lc[b], 1);
            words[pos] = ((unsigned int)ei[e] << 11) | (unsigned int)ls;
        }
    }
}

__global__ __launch_bounds__(1024) void k_lsort(const int* __restrict__ cursor,
                                                const unsigned int* __restrict__ words,
                                                int* __restrict__ seg_ptr,
                                                int* __restrict__ gidx) {
    __shared__ int h[2048];
    __shared__ int ps[1024];
    int tid = threadIdx.x;
    int b = blockIdx.x;
    int rb = b * CAP, re = cursor[b];
    h[tid] = 0; h[tid + 1024] = 0;
    __syncthreads();
    for (int e = rb + tid; e < re; e += 1024)
        atomicAdd(&h[words[e] & 2047u], 1);
    __syncthreads();
    int h0 = h[2 * tid], h1 = h[2 * tid + 1];
    ps[tid] = h0 + h1;
    __syncthreads();
    for (int off = 1; off < 1024; off <<= 1) {
        int t = (tid >= off) ? ps[tid - off] : 0;
        __syncthreads();
        ps[tid] += t;
        __syncthreads();
    }
    int pair_excl = ps[tid] - (h0 + h1);
    __syncthreads();
    int g0 = rb + pair_excl, g1 = g0 + h0;
    h[2 * tid] = g0; h[2 * tid + 1] = g1;
    int sb = b * SPB + 2 * tid;
    seg_ptr[sb] = g0;
    seg_ptr[sb + 1] = g1;
    if (tid == 1023) seg_ptr[b * SPB + 2048] = rb + ps[1023];
    __syncthreads();
    for (int e = rb + tid; e < re; e += 1024) {
        unsigned int w = words[e];
        int pos = atomicAdd(&h[w & 2047u], 1);
        gidx[pos] = (int)(w >> 11);
    }
}

// ---------------- prep kernels ----------------

// x[N][64] fp32 -> 4 slice tables xq[p][N][16] bf16 (3.2 MB each: L2-resident)
__global__ void k_cvt4(const float* __restrict__ x, unsigned short* __restrict__ xq) {
    int i = blockIdx.x * 256 + threadIdx.x;
    if (i >= N_NODES * 64) return;
    int node = i >> 6, f = i & 63;
    xq[((size_t)(f >> 4) * N_NODES + node) * 16 + (f & 15)] = f2bf(x[i]);
}

// W[512][64] -> B-fragment order: pos = ((c*16+ks)*64 + m + 16q)*8 + j
// Wssl[64][64] -> pos = ((c*2+ks)*64 + m + 16q)*8 + j
__global__ void k_wprep(const float* __restrict__ W1, const float* __restrict__ W2,
                        const float* __restrict__ Wssl,
                        unsigned short* __restrict__ Wf1, unsigned short* __restrict__ Wf2,
                        unsigned short* __restrict__ Wsf) {
    int i = blockIdx.x * 256 + threadIdx.x;
    if (i < 512 * 64) {
        int k = i >> 6, o = i & 63;
        int c = o >> 4, m = o & 15;
        int ks = k >> 5, q = (k >> 3) & 3, j = k & 7;
        int pos = (((c * 16 + ks) * 64) + (m + 16 * q)) * 8 + j;
        Wf1[pos] = f2bf(W1[i]);
        Wf2[pos] = f2bf(W2[i]);
    }
    if (i < 64 * 64) {
        int k = i >> 6, o = i & 63;
        int c = o >> 4, m = o & 15;
        int ks = k >> 5, q = (k >> 3) & 3, j = k & 7;   // ks in 0..1
        int pos = (((c * 2 + ks) * 64) + (m + 16 * q)) * 8 + j;
        Wsf[pos] = f2bf(Wssl[i]);
    }
}

// ---------------- sliced pull aggregation ----------------
// One wave per node; lanes = 4 edge-slots x 16 features of slice p.
// Gathers hit the 3.2 MB slice table (L2-resident). Writes agg[node][t*64 + p*16 + f].

__global__ __launch_bounds__(256) void k_agg4(const int* __restrict__ seg_ptr,
                                              const int* __restrict__ gidx,
                                              const unsigned short* __restrict__ xs,
                                              unsigned short* __restrict__ agg,
                                              int p_slice) {
    int wave = threadIdx.x >> 6, lane = threadIdx.x & 63;
    int n = blockIdx.x * 4 + wave;
    if (n >= N_NODES) return;
    int sel = lane >> 4, fl = lane & 15;
    int sb = (n >> 8) * SPB + (n & 255) * 8;
    int p[9];
#pragma unroll
    for (int t = 0; t < 9; ++t) p[t] = __builtin_amdgcn_readfirstlane(seg_ptr[sb + t]);
    int len[8], cl[8];
    int maxlen = 0;
#pragma unroll
    for (int t = 0; t < 8; ++t) {
        len[t] = p[t + 1] - p[t];
        int c = p[t + 1] - 1;
        cl[t] = c > 0 ? c : 0;
        maxlen = len[t] > maxlen ? len[t] : maxlen;
    }
    float a[8] = {0.f, 0.f, 0.f, 0.f, 0.f, 0.f, 0.f, 0.f};
#pragma unroll 2
    for (int k = 0; k < maxlen; k += 4) {
        int g[8];
#pragma unroll
        for (int t = 0; t < 8; ++t) {
            int idx = p[t] + k + sel;
            idx = idx < cl[t] ? idx : cl[t];
            g[t] = gidx[idx] & 0x1FFFF;         // mask pad garbage -> safe in-ws read
        }
#pragma unroll
        for (int t = 0; t < 8; ++t) {
            float x = bf2f(xs[((unsigned)g[t] << 4) + fl]);
            a[t] += ((k + sel) < len[t]) ? x : 0.f;
        }
    }
#pragma unroll
    for (int t = 0; t < 8; ++t) {
        a[t] += __shfl_xor(a[t], 16, 64);
        a[t] += __shfl_xor(a[t], 32, 64);
    }
    if (lane < 16) {
        unsigned short* o = agg + (size_t)n * 512 + p_slice * 16 + fl;
#pragma unroll
        for (int t = 0; t < 8; ++t) o[t * 64] = f2bf(a[t]);
    }
}

// ---------------- MFMA GEMM: h = relu(agg[N,512] @ W[512,64] + b) ----------------
// Wf pre-converted to fragment order in global (L1/L2-hot). No LDS, no barrier.

__global__ __launch_bounds__(256) void k_gemm(const unsigned short* __restrict__ agg,
                                              const unsigned short* __restrict__ Wf,
                                              const float* __restrict__ bias,
                                              unsigned short* __restrict__ bf_sliced,
                                              unsigned short* __restrict__ bf_flat,
                                              float* __restrict__ f32_flat) {
    int wave = threadIdx.x >> 6, lane = threadIdx.x & 63;
    int tile = blockIdx.x * 4 + wave;
    if (tile >= NTILES) return;
    int m = lane & 15, q = lane >> 4;
    const unsigned short* arow = agg + ((size_t)(tile * 16 + m)) * 512 + q * 8;
    floatx4 acc[4];
    for (int c = 0; c < 4; ++c) acc[c] = (floatx4){0.f, 0.f, 0.f, 0.f};
    const short8* wf8 = (const short8*)Wf;
#pragma unroll
    for (int ks = 0; ks < 16; ++ks) {
        short8 a = *(const short8*)(arow + ks * 32);
#pragma unroll
        for (int c = 0; c < 4; ++c) {
            short8 b = wf8[(c * 16 + ks) * 64 + lane];
            acc[c] = __builtin_amdgcn_mfma_f32_16x16x32_bf16(a, b, acc[c], 0, 0, 0);
        }
    }
    int node0 = tile * 16;
#pragma unroll
    for (int c = 0; c < 4; ++c) {
        float bb = bias[c * 16 + m];
#pragma unroll
        for (int i = 0; i < 4; ++i) {
            float v = acc[c][i] + bb;
            v = v > 0.f ? v : 0.f;
            int node = node0 + q * 4 + i;                 // C/D: row = quad*4 + reg
            unsigned short vb = f2bf(v);
            if (bf_sliced) bf_sliced[((size_t)c * N_NODES + node) * 16 + m] = vb;
            if (bf_flat)   bf_flat[(size_t)node * 64 + c * 16 + m] = vb;
            if (f32_flat)  f32_flat[(size_t)node * 64 + c * 16 + m] = v;
        }
    }
}

// ---------------- SSL via MFMA: out = h2[N,64] @ Wssl[64,64] + bssl ----------------

__global__ __launch_bounds__(256) void k_sslm(const unsigned short* __restrict__ h2b,
                                              const unsigned short* __restrict__ Wsf,
                                              const float* __restrict__ bssl,
                                              float* __restrict__ out) {
    int wave = threadIdx.x >> 6, lane = threadIdx.x & 63;
    int tile = blockIdx.x * 4 + wave;
    if (tile >= NTILES) return;
    int m = lane & 15, q = lane >> 4;
    const unsigned short* arow = h2b + ((size_t)(tile * 16 + m)) * 64 + q * 8;
    floatx4 acc[4];
    for (int c = 0; c < 4; ++c) acc[c] = (floatx4){0.f, 0.f, 0.f, 0.f};
    const short8* wf8 = (const short8*)Wsf;
#pragma unroll
    for (int ks = 0; ks < 2; ++ks) {
        short8 a = *(const short8*)(arow + ks * 32);
#pragma unroll
        for (int c = 0; c < 4; ++c) {
            short8 b = wf8[(c * 2 + ks) * 64 + lane];
            acc[c] = __builtin_amdgcn_mfma_f32_16x16x32_bf16(a, b, acc[c], 0, 0, 0);
        }
    }
    int node0 = tile * 16;
#pragma unroll
    for (int c = 0; c < 4; ++c) {
        float bb = bssl[c * 16 + m];
#pragma unroll
        for (int i = 0; i < 4; ++i) {
            int node = node0 + q * 4 + i;
            out[(size_t)node * 64 + c * 16 + m] = acc[c][i] + bb;
        }
    }
}

// ---------------- launch ----------------

extern "C" void kernel_launch(void* const* d_in, const int* in_sizes, int n_in,
                              void* d_out, int out_size, void* d_ws, size_t ws_size,
                              hipStream_t stream) {
    const float* x    = (const float*)d_in[0];
    const int*   ei   = (const int*)d_in[1];   // [2,E]: row0 src, row1 dst
    const int*   ti   = (const int*)d_in[2];
    const float* W1   = (const float*)d_in[3];
    const float* b1   = (const float*)d_in[4];
    const float* W2   = (const float*)d_in[5];
    const float* b2   = (const float*)d_in[6];
    const float* Wssl = (const float*)d_in[7];
    const float* bssl = (const float*)d_in[8];
    float* out = (float*)d_out;

    char* w = (char*)d_ws;
    auto alloc = [&](size_t bytes) -> char* {
        char* p = w;
        w += (bytes + 255) & ~(size_t)255;
        return p;
    };
    int* cursor   = (int*)alloc((size_t)NBP * 4);
    unsigned int* words = (unsigned int*)alloc((size_t)NB * CAP * 4);
    int* seg_ptr  = (int*)alloc((size_t)NB * SPB * 4);
    int* gidx     = (int*)alloc((size_t)NB * CAP * 4);
    unsigned short* xq  = (unsigned short*)alloc((size_t)4 * N_NODES * 16 * 2);
    unsigned short* h1q = (unsigned short*)alloc((size_t)4 * N_NODES * 16 * 2);
    unsigned short* h2b = (unsigned short*)alloc((size_t)N_NODES * 64 * 2);
    unsigned short* Wf1 = (unsigned short*)alloc((size_t)512 * 64 * 2);
    unsigned short* Wf2 = (unsigned short*)alloc((size_t)512 * 64 * 2);
    unsigned short* Wsf = (unsigned short*)alloc((size_t)64 * 64 * 2);
    unsigned short* agg = (unsigned short*)alloc((size_t)N_NODES * 512 * 2);

    int nbe = (N_EDGES + 8191) / 8192;   // 391 edge-blocks

    k_init<<<1, 512, 0, stream>>>(cursor);
    k_bscatter<<<nbe, 1024, 0, stream>>>(ei, ti, cursor, words);
    k_lsort<<<NB, 1024, 0, stream>>>(cursor, words, seg_ptr, gidx);
    k_cvt4<<<(N_NODES * 64 + 255) / 256, 256, 0, stream>>>(x, xq);
    k_wprep<<<(512 * 64 + 255) / 256, 256, 0, stream>>>(W1, W2, Wssl, Wf1, Wf2, Wsf);

    int nagg = (N_NODES + 3) / 4;
    int ngem = (NTILES + 3) / 4;

    // conv1: 4 slice-resident agg passes over xq, then GEMM -> h1 slices (bf16)
    for (int p = 0; p < 4; ++p)
        k_agg4<<<nagg, 256, 0, stream>>>(seg_ptr, gidx, xq + (size_t)p * N_NODES * 16, agg, p);
    k_gemm<<<ngem, 256, 0, stream>>>(agg, Wf1, b1, h1q, nullptr, nullptr);

    // conv2: 4 slice-resident agg passes over h1q, then GEMM -> d_out fp32 + h2b bf16
    for (int p = 0; p < 4; ++p)
        k_agg4<<<nagg, 256, 0, stream>>>(seg_ptr, gidx, h1q + (size_t)p * N_NODES * 16, agg, p);
    k_gemm<<<ngem, 256, 0, stream>>>(agg, Wf2, b2, nullptr, h2b, out);

    // ssl: h2 @ Wssl + bssl (MFMA)
    k_sslm<<<ngem, 256, 0, stream>>>(h2b, Wsf, bssl, out + (size_t)N_NODES * 64);
}

// Round 7
// 415.549 us; speedup vs baseline: 1.5997x; 1.5997x over previous
//
#include <hip/hip_runtime.h>
#include <hip/hip_bf16.h>

#define N_NODES 100000
#define N_EDGES 3200000
#define NB 391                         // ceil(100000/256) buckets of 256 nodes
#define NBP 400                        // padded
#define CAP 9216                       // fixed bucket capacity: mean 8184 + 11.4 sigma
#define SPB 2049                       // seg_ptr entries per bucket
#define NTILES 6250                    // 100000 / 16
#define AROW 520                       // LDS A-tile row pitch in shorts (16B-aligned, bank-uniform)

typedef __attribute__((ext_vector_type(8))) short short8;
typedef __attribute__((ext_vector_type(4))) float floatx4;

__device__ __forceinline__ float bf2f(unsigned short u) {
    unsigned int x = ((unsigned int)u) << 16;
    return __builtin_bit_cast(float, x);
}
__device__ __forceinline__ unsigned short f2bf(float f) {
    unsigned int u = __builtin_bit_cast(unsigned int, f);
    unsigned int r = (u + 0x7FFFu + ((u >> 16) & 1u)) >> 16;
    return (unsigned short)r;
}

// ============ fixed-capacity bucketed sort by segment (dst*8+t) ============

__global__ __launch_bounds__(512) void k_init(int* __restrict__ cursor) {
    int tid = threadIdx.x;
    if (tid < NB) cursor[tid] = tid * CAP;
}

// single-pass: per-edge (bucket, word, local ofs) held in registers across the barrier
__global__ __launch_bounds__(1024) void k_bscatter(const int* __restrict__ ei,
                                                   const int* __restrict__ ti,
                                                   int* __restrict__ cursor,
                                                   unsigned int* __restrict__ words) {
    __shared__ int h[NBP];
    __shared__ int bb[NBP];
    int tid = threadIdx.x;
    if (tid < NBP) h[tid] = 0;
    __syncthreads();
    int base = blockIdx.x * 4096;
    int breg[4], ofs[4];
    unsigned wreg[4];
#pragma unroll
    for (int i = 0; i < 4; ++i) {
        int e = base + i * 1024 + tid;
        bool v = e < N_EDGES;
        int dst = v ? ei[N_EDGES + e] : 0;
        int src = v ? ei[e] : 0;
        int tt  = v ? ti[e] : 0;
        int b = dst >> 8;
        breg[i] = v ? b : -1;
        wreg[i] = ((unsigned)src << 11) | ((unsigned)(dst & 255) << 3) | (unsigned)tt;
        ofs[i] = v ? atomicAdd(&h[b], 1) : 0;
    }
    __syncthreads();
    if (tid < NB) {
        int c = h[tid];
        bb[tid] = c ? atomicAdd(&cursor[tid], c) : 0;
    }
    __syncthreads();
#pragma unroll
    for (int i = 0; i < 4; ++i)
        if (breg[i] >= 0) words[bb[breg[i]] + ofs[i]] = wreg[i];
}

// single-pass per-bucket local sort -> seg_ptr[NB][2049] + gidx (bucket-local)
__global__ __launch_bounds__(1024) void k_lsort(const int* __restrict__ cursor,
                                                const unsigned int* __restrict__ words,
                                                int* __restrict__ seg_ptr,
                                                int* __restrict__ gidx) {
    __shared__ int h[2048];       // counts -> segment base
    __shared__ int ps[1024];
    int tid = threadIdx.x;
    int b = blockIdx.x;
    int rb = b * CAP, re = cursor[b];
    h[tid] = 0; h[tid + 1024] = 0;
    __syncthreads();
    unsigned wreg[9];
    int ofs[9];
#pragma unroll
    for (int i = 0; i < 9; ++i) {
        int e = rb + i * 1024 + tid;
        bool v = e < re;
        unsigned w = v ? words[e] : 0u;
        wreg[i] = w;
        ofs[i] = v ? atomicAdd(&h[w & 2047u], 1) : -1;
    }
    __syncthreads();
    int h0 = h[2 * tid], h1 = h[2 * tid + 1];
    ps[tid] = h0 + h1;
    __syncthreads();
    for (int off = 1; off < 1024; off <<= 1) {
        int t = (tid >= off) ? ps[tid - off] : 0;
        __syncthreads();
        ps[tid] += t;
        __syncthreads();
    }
    int pair_excl = ps[tid] - (h0 + h1);
    __syncthreads();
    int g0 = rb + pair_excl, g1 = g0 + h0;
    h[2 * tid] = g0; h[2 * tid + 1] = g1;   // counts -> bases (ofs already captured)
    int sb = b * SPB + 2 * tid;
    seg_ptr[sb] = g0;
    seg_ptr[sb + 1] = g1;
    if (tid == 1023) seg_ptr[b * SPB + 2048] = rb + ps[1023];
    __syncthreads();
#pragma unroll
    for (int i = 0; i < 9; ++i)
        if (ofs[i] >= 0) {
            unsigned w = wreg[i];
            gidx[h[w & 2047u] + ofs[i]] = (int)(w >> 11);
        }
}

// ---------------- prep kernels ----------------

__global__ void k_cvt(const float* __restrict__ x, unsigned short* __restrict__ xb) {
    int i = blockIdx.x * 256 + threadIdx.x;
    if (i < N_NODES * 64) xb[i] = f2bf(x[i]);
}

// W[512][64] -> B-fragment order; Wssl[64][64] likewise
__global__ void k_wprep(const float* __restrict__ W1, const float* __restrict__ W2,
                        const float* __restrict__ Wssl,
                        unsigned short* __restrict__ Wf1, unsigned short* __restrict__ Wf2,
                        unsigned short* __restrict__ Wsf) {
    int i = blockIdx.x * 256 + threadIdx.x;
    if (i < 512 * 64) {
        int k = i >> 6, o = i & 63;
        int c = o >> 4, m = o & 15;
        int ks = k >> 5, q = (k >> 3) & 3, j = k & 7;
        int pos = (((c * 16 + ks) * 64) + (m + 16 * q)) * 8 + j;
        Wf1[pos] = f2bf(W1[i]);
        Wf2[pos] = f2bf(W2[i]);
    }
    if (i < 64 * 64) {
        int k = i >> 6, o = i & 63;
        int c = o >> 4, m = o & 15;
        int ks = k >> 5, q = (k >> 3) & 3, j = k & 7;
        int pos = (((c * 2 + ks) * 64) + (m + 16 * q)) * 8 + j;
        Wsf[pos] = f2bf(Wssl[i]);
    }
}

// ---------------- fused conv: dword-gather agg -> LDS A-tile -> MFMA -> relu ----------------
// Gather: lane = (edge-slot sel2 = lane>>5) x (feature-pair fp = lane&31).
// One dword load = 2 bf16 features; 32 lanes/edge; 2 edges per instruction.
// Edge ids stay scalar (s_load g0,g1 per t; per-lane cndmask select).
// LDS A-tile row-major [32 nodes][AROW=520 shorts]: writes contiguous (0 conflicts),
// b128 reads 16B-aligned, uniform 8 lanes/bank-quad (optimal).

__global__ __launch_bounds__(512) void k_fused(const int* __restrict__ seg_ptr,
                                               const int* __restrict__ gidx,
                                               const unsigned short* __restrict__ xb,
                                               const unsigned short* __restrict__ Wf,
                                               const float* __restrict__ bias,
                                               unsigned short* __restrict__ out_bf,
                                               float* __restrict__ out_f32) {
    __shared__ __align__(16) unsigned short Atile[32 * AROW];   // 33280 B
    int tid = threadIdx.x;
    int wave = tid >> 6, lane = tid & 63;
    int node_base = blockIdx.x * 32;
    int sel2 = lane >> 5, fp = lane & 31;
    const unsigned int* xs32 = (const unsigned int*)xb;

    for (int i = 0; i < 4; ++i) {                 // 4 nodes per wave
        int nl = wave * 4 + i;                    // 0..31
        int n = node_base + nl;
        int sb = (n >> 8) * SPB + (n & 255) * 8;
        int p[9];
#pragma unroll
        for (int t = 0; t < 9; ++t) p[t] = __builtin_amdgcn_readfirstlane(seg_ptr[sb + t]);
        int len[8], cl[8];
        int maxlen = 0;
#pragma unroll
        for (int t = 0; t < 8; ++t) {
            len[t] = p[t + 1] - p[t];
            int c = p[t + 1] - 1;
            cl[t] = c > 0 ? c : 0;
            maxlen = len[t] > maxlen ? len[t] : maxlen;
        }
        float ax[8] = {0.f, 0.f, 0.f, 0.f, 0.f, 0.f, 0.f, 0.f};
        float ay[8] = {0.f, 0.f, 0.f, 0.f, 0.f, 0.f, 0.f, 0.f};
#pragma unroll 2
        for (int k = 0; k < maxlen; k += 2) {
            int ge[8];
#pragma unroll
            for (int t = 0; t < 8; ++t) {
                int i0 = p[t] + k;     i0 = i0 < cl[t] ? i0 : cl[t];
                int i1 = p[t] + k + 1; i1 = i1 < cl[t] ? i1 : cl[t];
                int g0 = __builtin_amdgcn_readfirstlane(gidx[i0]) & 0x1FFFF;
                int g1 = __builtin_amdgcn_readfirstlane(gidx[i1]) & 0x1FFFF;
                ge[t] = sel2 ? g1 : g0;
            }
            unsigned pk[8];
#pragma unroll
            for (int t = 0; t < 8; ++t)
                pk[t] = xs32[((unsigned)ge[t] << 5) + fp];
#pragma unroll
            for (int t = 0; t < 8; ++t) {
                unsigned v = ((k + sel2) < len[t]) ? pk[t] : 0u;
                ax[t] += __builtin_bit_cast(float, v << 16);
                ay[t] += __builtin_bit_cast(float, v & 0xFFFF0000u);
            }
        }
        // reduce edge-slot pair (lane ^ 32)
#pragma unroll
        for (int t = 0; t < 8; ++t) {
            ax[t] += __shfl_xor(ax[t], 32, 64);
            ay[t] += __shfl_xor(ay[t], 32, 64);
        }
        if (lane < 32) {
            unsigned int* row = (unsigned int*)&Atile[nl * AROW];
#pragma unroll
            for (int t = 0; t < 8; ++t) {
                unsigned pkd = (unsigned)f2bf(ax[t]) | ((unsigned)f2bf(ay[t]) << 16);
                row[t * 32 + fp] = pkd;        // features (2fp, 2fp+1) of block t
            }
        }
    }
    __syncthreads();

    // GEMM: wave -> (node-tile nt = wave>>2, col-tile c = wave&3), 16 MFMA
    int nt = wave >> 2, c = wave & 3;
    int m = lane & 15, q = lane >> 4;
    floatx4 acc = (floatx4){0.f, 0.f, 0.f, 0.f};
    const short8* wf8 = (const short8*)Wf;
    const unsigned short* abase = &Atile[(nt * 16 + m) * AROW + q * 8];
#pragma unroll
    for (int ks = 0; ks < 16; ++ks) {
        short8 a = *(const short8*)(abase + ks * 32);
        short8 b = wf8[(c * 16 + ks) * 64 + lane];
        acc = __builtin_amdgcn_mfma_f32_16x16x32_bf16(a, b, acc, 0, 0, 0);
    }
    float bb = bias[c * 16 + m];
    int node0 = node_base + nt * 16;
#pragma unroll
    for (int i = 0; i < 4; ++i) {
        float v = acc[i] + bb;
        v = v > 0.f ? v : 0.f;
        int node = node0 + q * 4 + i;                 // C/D: row = quad*4 + reg
        size_t idx = (size_t)node * 64 + c * 16 + m;  //      col = lane&15
        if (out_bf)  out_bf[idx] = f2bf(v);
        if (out_f32) out_f32[idx] = v;
    }
}

// ---------------- SSL via MFMA: out = h2[N,64] @ Wssl[64,64] + bssl ----------------

__global__ __launch_bounds__(256) void k_sslm(const unsigned short* __restrict__ h2b,
                                              const unsigned short* __restrict__ Wsf,
                                              const float* __restrict__ bssl,
                                              float* __restrict__ out) {
    int wave = threadIdx.x >> 6, lane = threadIdx.x & 63;
    int tile = blockIdx.x * 4 + wave;
    if (tile >= NTILES) return;
    int m = lane & 15, q = lane >> 4;
    const unsigned short* arow = h2b + ((size_t)(tile * 16 + m)) * 64 + q * 8;
    floatx4 acc[4];
    for (int c = 0; c < 4; ++c) acc[c] = (floatx4){0.f, 0.f, 0.f, 0.f};
    const short8* wf8 = (const short8*)Wsf;
#pragma unroll
    for (int ks = 0; ks < 2; ++ks) {
        short8 a = *(const short8*)(arow + ks * 32);
#pragma unroll
        for (int c = 0; c < 4; ++c) {
            short8 b = wf8[(c * 2 + ks) * 64 + lane];
            acc[c] = __builtin_amdgcn_mfma_f32_16x16x32_bf16(a, b, acc[c], 0, 0, 0);
        }
    }
    int node0 = tile * 16;
#pragma unroll
    for (int c = 0; c < 4; ++c) {
        float bb = bssl[c * 16 + m];
#pragma unroll
        for (int i = 0; i < 4; ++i) {
            int node = node0 + q * 4 + i;
            out[(size_t)node * 64 + c * 16 + m] = acc[c][i] + bb;
        }
    }
}

// ---------------- launch ----------------

extern "C" void kernel_launch(void* const* d_in, const int* in_sizes, int n_in,
                              void* d_out, int out_size, void* d_ws, size_t ws_size,
                              hipStream_t stream) {
    const float* x    = (const float*)d_in[0];
    const int*   ei   = (const int*)d_in[1];   // [2,E]: row0 src, row1 dst
    const int*   ti   = (const int*)d_in[2];
    const float* W1   = (const float*)d_in[3];
    const float* b1   = (const float*)d_in[4];
    const float* W2   = (const float*)d_in[5];
    const float* b2   = (const float*)d_in[6];
    const float* Wssl = (const float*)d_in[7];
    const float* bssl = (const float*)d_in[8];
    float* out = (float*)d_out;

    char* w = (char*)d_ws;
    auto alloc = [&](size_t bytes) -> char* {
        char* p = w;
        w += (bytes + 255) & ~(size_t)255;
        return p;
    };
    int* cursor   = (int*)alloc((size_t)NBP * 4);
    unsigned int* words = (unsigned int*)alloc((size_t)NB * CAP * 4);
    int* seg_ptr  = (int*)alloc((size_t)NB * SPB * 4);
    int* gidx     = (int*)alloc((size_t)NB * CAP * 4);
    unsigned short* xb  = (unsigned short*)alloc((size_t)N_NODES * 64 * 2);
    unsigned short* h1b = (unsigned short*)alloc((size_t)N_NODES * 64 * 2);
    unsigned short* h2b = (unsigned short*)alloc((size_t)N_NODES * 64 * 2);
    unsigned short* Wf1 = (unsigned short*)alloc((size_t)512 * 64 * 2);
    unsigned short* Wf2 = (unsigned short*)alloc((size_t)512 * 64 * 2);
    unsigned short* Wsf = (unsigned short*)alloc((size_t)64 * 64 * 2);

    k_init<<<1, 512, 0, stream>>>(cursor);
    k_bscatter<<<(N_EDGES + 4095) / 4096, 1024, 0, stream>>>(ei, ti, cursor, words);
    k_lsort<<<NB, 1024, 0, stream>>>(cursor, words, seg_ptr, gidx);
    k_cvt<<<(N_NODES * 64 + 255) / 256, 256, 0, stream>>>(x, xb);
    k_wprep<<<(512 * 64 + 255) / 256, 256, 0, stream>>>(W1, W2, Wssl, Wf1, Wf2, Wsf);

    // conv1 fused: agg(xb) + GEMM W1 + relu -> h1b (bf16)
    k_fused<<<N_NODES / 32, 512, 0, stream>>>(seg_ptr, gidx, xb, Wf1, b1, h1b, nullptr);
    // conv2 fused: agg(h1b) + GEMM W2 + relu -> d_out fp32 + h2b bf16
    k_fused<<<N_NODES / 32, 512, 0, stream>>>(seg_ptr, gidx, h1b, Wf2, b2, h2b, out);

    // ssl: h2 @ Wssl + bssl (MFMA)
    k_sslm<<<(NTILES + 3) / 4, 256, 0, stream>>>(h2b, Wsf, bssl, out + (size_t)N_NODES * 64);
}

// Round 8
// 348.012 us; speedup vs baseline: 1.9101x; 1.1941x over previous
//
#include <hip/hip_runtime.h>
#include <hip/hip_bf16.h>

#define N_NODES 100000
#define N_EDGES 3200000
#define NB 391                         // ceil(100000/256) buckets of 256 nodes
#define NBP 400                        // padded
#define CAP 9216                       // fixed bucket capacity: mean 8184 + 11.4 sigma
#define PCAP 20480                     // padded-layout ints per bucket (mean ~16.6K + 23 sigma)
#define ZNODE N_NODES                  // dummy node index -> all-zeros feature row
#define NTILES 6250                    // 100000 / 16
#define AROW 520                       // LDS A-tile row pitch in shorts (16B-aligned, bank-uniform)

typedef __attribute__((ext_vector_type(8))) short short8;
typedef __attribute__((ext_vector_type(4))) float floatx4;

__device__ __forceinline__ float bf2f(unsigned short u) {
    unsigned int x = ((unsigned int)u) << 16;
    return __builtin_bit_cast(float, x);
}
__device__ __forceinline__ unsigned short f2bf(float f) {
    unsigned int u = __builtin_bit_cast(unsigned int, f);
    unsigned int r = (u + 0x7FFFu + ((u >> 16) & 1u)) >> 16;
    return (unsigned short)r;
}

// ============ bucketed sort by segment (dst*8+t) -> padded node-major layout ============

__global__ __launch_bounds__(512) void k_init(int* __restrict__ cursor) {
    int tid = threadIdx.x;
    if (tid < NB) cursor[tid] = tid * CAP;
}

// single-pass: per-edge (bucket, word, local ofs) held in registers across the barrier
__global__ __launch_bounds__(1024) void k_bscatter(const int* __restrict__ ei,
                                                   const int* __restrict__ ti,
                                                   int* __restrict__ cursor,
                                                   unsigned int* __restrict__ words) {
    __shared__ int h[NBP];
    __shared__ int bb[NBP];
    int tid = threadIdx.x;
    if (tid < NBP) h[tid] = 0;
    __syncthreads();
    int base = blockIdx.x * 4096;
    int breg[4], ofs[4];
    unsigned wreg[4];
#pragma unroll
    for (int i = 0; i < 4; ++i) {
        int e = base + i * 1024 + tid;
        bool v = e < N_EDGES;
        int dst = v ? ei[N_EDGES + e] : 0;
        int src = v ? ei[e] : 0;
        int tt  = v ? ti[e] : 0;
        int b = dst >> 8;
        breg[i] = v ? b : -1;
        wreg[i] = ((unsigned)src << 11) | ((unsigned)(dst & 255) << 3) | (unsigned)tt;
        ofs[i] = v ? atomicAdd(&h[b], 1) : 0;
    }
    __syncthreads();
    if (tid < NB) {
        int c = h[tid];
        bb[tid] = c ? atomicAdd(&cursor[tid], c) : 0;
    }
    __syncthreads();
#pragma unroll
    for (int i = 0; i < 4; ++i)
        if (breg[i] >= 0) words[bb[breg[i]] + ofs[i]] = wreg[i];
}

// per-bucket: histogram -> per-node padded maxlen -> zero-fill -> scatter into
// gid_pad[node][k][t] (t fastest). Pad slots hold ZNODE (zeros row). Emits
// node_pm[n] = (pbase, maxlen_padded).
__global__ __launch_bounds__(1024) void k_lsort(const int* __restrict__ cursor,
                                                const unsigned int* __restrict__ words,
                                                int2* __restrict__ node_pm,
                                                int* __restrict__ gid_pad) {
    __shared__ int h[2048];
    __shared__ int ps[1024];
    __shared__ int nb[256];
    int tid = threadIdx.x;
    int b = blockIdx.x;
    int rb = b * CAP, re = cursor[b];
    h[tid] = 0; h[tid + 1024] = 0;
    __syncthreads();
    unsigned wreg[9];
    int ofs[9];
#pragma unroll
    for (int i = 0; i < 9; ++i) {
        int e = rb + i * 1024 + tid;
        bool v = e < re;
        unsigned w = v ? words[e] : 0u;
        wreg[i] = w;
        ofs[i] = v ? atomicAdd(&h[w & 2047u], 1) : -1;
    }
    __syncthreads();
    // per-node padded region size in ints: align2(maxlen) * 8
    int sz = 0;
    if (tid < 256) {
        int m = 0;
#pragma unroll
        for (int t = 0; t < 8; ++t) { int c = h[tid * 8 + t]; m = c > m ? c : m; }
        m = (m + 1) & ~1;              // even maxlen -> k-pair loop needs no tail
        sz = m * 8;
    }
    ps[tid] = sz;
    __syncthreads();
    for (int off = 1; off < 1024; off <<= 1) {
        int t = (tid >= off) ? ps[tid - off] : 0;
        __syncthreads();
        ps[tid] += t;
        __syncthreads();
    }
    if (tid < 256) nb[tid] = ps[tid] - sz;
    __syncthreads();
    int bsz = ps[1023];
    int pbase = b * PCAP;
    for (int s = tid; s < bsz; s += 1024) gid_pad[pbase + s] = ZNODE;
    int gn = b * 256 + tid;
    if (tid < 256 && gn < N_NODES) node_pm[gn] = (int2){pbase + nb[tid], sz >> 3};
    __syncthreads();
#pragma unroll
    for (int i = 0; i < 9; ++i)
        if (ofs[i] >= 0) {
            unsigned w = wreg[i];
            int ls = (int)(w & 2047u);
            gid_pad[pbase + nb[ls >> 3] + ofs[i] * 8 + (ls & 7)] = (int)(w >> 11);
        }
}

// ---------------- prep kernels ----------------

// convert x -> bf16 (row ZNODE zeroed); also zero h1b's ZNODE row for conv2 gathers
__global__ void k_cvt(const float* __restrict__ x, unsigned short* __restrict__ xb,
                      unsigned short* __restrict__ h1b) {
    int i = blockIdx.x * 256 + threadIdx.x;
    if (i < N_NODES * 64) xb[i] = f2bf(x[i]);
    if (i < 64) {
        xb[(size_t)ZNODE * 64 + i] = 0;
        h1b[(size_t)ZNODE * 64 + i] = 0;
    }
}

// W[512][64] -> B-fragment order; Wssl[64][64] likewise
__global__ void k_wprep(const float* __restrict__ W1, const float* __restrict__ W2,
                        const float* __restrict__ Wssl,
                        unsigned short* __restrict__ Wf1, unsigned short* __restrict__ Wf2,
                        unsigned short* __restrict__ Wsf) {
    int i = blockIdx.x * 256 + threadIdx.x;
    if (i < 512 * 64) {
        int k = i >> 6, o = i & 63;
        int c = o >> 4, m = o & 15;
        int ks = k >> 5, q = (k >> 3) & 3, j = k & 7;
        int pos = (((c * 16 + ks) * 64) + (m + 16 * q)) * 8 + j;
        Wf1[pos] = f2bf(W1[i]);
        Wf2[pos] = f2bf(W2[i]);
    }
    if (i < 64 * 64) {
        int k = i >> 6, o = i & 63;
        int c = o >> 4, m = o & 15;
        int ks = k >> 5, q = (k >> 3) & 3, j = k & 7;
        int pos = (((c * 2 + ks) * 64) + (m + 16 * q)) * 8 + j;
        Wsf[pos] = f2bf(Wssl[i]);
    }
}

// ---------------- fused conv: padded dword-gather agg -> LDS A-tile -> MFMA -> relu ----------------
// Gather: lane = (edge-slot sel2 = lane>>5) x (feature-pair fp = lane&31).
// Edge ids come from gid_pad[node][k][t] via per-lane vector dword loads (L1-hot
// stream, 2 distinct addrs/wave). Pad slots are ZNODE -> zeros row -> unconditional add.
// No predication, no clamps, no per-node pointer preamble.

__global__ __launch_bounds__(512) void k_fused(const int2* __restrict__ node_pm,
                                               const int* __restrict__ gid_pad,
                                               const unsigned short* __restrict__ xb,
                                               const unsigned short* __restrict__ Wf,
                                               const float* __restrict__ bias,
                                               unsigned short* __restrict__ out_bf,
                                               float* __restrict__ out_f32) {
    __shared__ __align__(16) unsigned short Atile[32 * AROW];   // 33280 B
    int tid = threadIdx.x;
    int wave = tid >> 6, lane = tid & 63;
    int node_base = blockIdx.x * 32;
    int sel2 = lane >> 5, fp = lane & 31;
    int lofs = sel2 * 8;                        // per-lane slot offset into gid_pad
    const unsigned int* xs32 = (const unsigned int*)xb;

    for (int i = 0; i < 4; ++i) {               // 4 nodes per wave
        int nl = wave * 4 + i;                  // 0..31
        int n = node_base + nl;
        int2 pm = node_pm[n];
        int pb = __builtin_amdgcn_readfirstlane(pm.x);
        int ml = __builtin_amdgcn_readfirstlane(pm.y);   // even
        const int* gp = gid_pad + pb;
        float ax[8] = {0.f, 0.f, 0.f, 0.f, 0.f, 0.f, 0.f, 0.f};
        float ay[8] = {0.f, 0.f, 0.f, 0.f, 0.f, 0.f, 0.f, 0.f};
#pragma unroll 2
        for (int k = 0; k < ml; k += 2) {
            int kb = k * 8 + lofs;
            int ge[8];
#pragma unroll
            for (int t = 0; t < 8; ++t) ge[t] = gp[kb + t];
            unsigned pk[8];
#pragma unroll
            for (int t = 0; t < 8; ++t) pk[t] = xs32[((unsigned)ge[t] << 5) + fp];
#pragma unroll
            for (int t = 0; t < 8; ++t) {
                ax[t] += __builtin_bit_cast(float, pk[t] << 16);
                ay[t] += __builtin_bit_cast(float, pk[t] & 0xFFFF0000u);
            }
        }
        // reduce edge-slot pair (lane ^ 32)
#pragma unroll
        for (int t = 0; t < 8; ++t) {
            ax[t] += __shfl_xor(ax[t], 32, 64);
            ay[t] += __shfl_xor(ay[t], 32, 64);
        }
        if (lane < 32) {
            unsigned int* row = (unsigned int*)&Atile[nl * AROW];
#pragma unroll
            for (int t = 0; t < 8; ++t) {
                unsigned pkd = (unsigned)f2bf(ax[t]) | ((unsigned)f2bf(ay[t]) << 16);
                row[t * 32 + fp] = pkd;        // features (2fp, 2fp+1) of block t
            }
        }
    }
    __syncthreads();

    // GEMM: wave -> (node-tile nt = wave>>2, col-tile c = wave&3), 16 MFMA
    int nt = wave >> 2, c = wave & 3;
    int m = lane & 15, q = lane >> 4;
    floatx4 acc = (floatx4){0.f, 0.f, 0.f, 0.f};
    const short8* wf8 = (const short8*)Wf;
    const unsigned short* abase = &Atile[(nt * 16 + m) * AROW + q * 8];
#pragma unroll
    for (int ks = 0; ks < 16; ++ks) {
        short8 a = *(const short8*)(abase + ks * 32);
        short8 b = wf8[(c * 16 + ks) * 64 + lane];
        acc = __builtin_amdgcn_mfma_f32_16x16x32_bf16(a, b, acc, 0, 0, 0);
    }
    float bb = bias[c * 16 + m];
    int node0 = node_base + nt * 16;
#pragma unroll
    for (int i = 0; i < 4; ++i) {
        float v = acc[i] + bb;
        v = v > 0.f ? v : 0.f;
        int node = node0 + q * 4 + i;                 // C/D: row = quad*4 + reg
        size_t idx = (size_t)node * 64 + c * 16 + m;  //      col = lane&15
        if (out_bf)  out_bf[idx] = f2bf(v);
        if (out_f32) out_f32[idx] = v;
    }
}

// ---------------- SSL via MFMA: out = h2[N,64] @ Wssl[64,64] + bssl ----------------

__global__ __launch_bounds__(256) void k_sslm(const unsigned short* __restrict__ h2b,
                                              const unsigned short* __restrict__ Wsf,
                                              const float* __restrict__ bssl,
                                              float* __restrict__ out) {
    int wave = threadIdx.x >> 6, lane = threadIdx.x & 63;
    int tile = blockIdx.x * 4 + wave;
    if (tile >= NTILES) return;
    int m = lane & 15, q = lane >> 4;
    const unsigned short* arow = h2b + ((size_t)(tile * 16 + m)) * 64 + q * 8;
    floatx4 acc[4];
    for (int c = 0; c < 4; ++c) acc[c] = (floatx4){0.f, 0.f, 0.f, 0.f};
    const short8* wf8 = (const short8*)Wsf;
#pragma unroll
    for (int ks = 0; ks < 2; ++ks) {
        short8 a = *(const short8*)(arow + ks * 32);
#pragma unroll
        for (int c = 0; c < 4; ++c) {
            short8 b = wf8[(c * 2 + ks) * 64 + lane];
            acc[c] = __builtin_amdgcn_mfma_f32_16x16x32_bf16(a, b, acc[c], 0, 0, 0);
        }
    }
    int node0 = tile * 16;
#pragma unroll
    for (int c = 0; c < 4; ++c) {
        float bb = bssl[c * 16 + m];
#pragma unroll
        for (int i = 0; i < 4; ++i) {
            int node = node0 + q * 4 + i;
            out[(size_t)node * 64 + c * 16 + m] = acc[c][i] + bb;
        }
    }
}

// ---------------- launch ----------------

extern "C" void kernel_launch(void* const* d_in, const int* in_sizes, int n_in,
                              void* d_out, int out_size, void* d_ws, size_t ws_size,
                              hipStream_t stream) {
    const float* x    = (const float*)d_in[0];
    const int*   ei   = (const int*)d_in[1];   // [2,E]: row0 src, row1 dst
    const int*   ti   = (const int*)d_in[2];
    const float* W1   = (const float*)d_in[3];
    const float* b1   = (const float*)d_in[4];
    const float* W2   = (const float*)d_in[5];
    const float* b2   = (const float*)d_in[6];
    const float* Wssl = (const float*)d_in[7];
    const float* bssl = (const float*)d_in[8];
    float* out = (float*)d_out;

    char* w = (char*)d_ws;
    auto alloc = [&](size_t bytes) -> char* {
        char* p = w;
        w += (bytes + 255) & ~(size_t)255;
        return p;
    };
    int* cursor   = (int*)alloc((size_t)NBP * 4);
    unsigned int* words = (unsigned int*)alloc((size_t)NB * CAP * 4);
    int2* node_pm = (int2*)alloc((size_t)N_NODES * 8);
    int* gid_pad  = (int*)alloc((size_t)NB * PCAP * 4);
    unsigned short* xb  = (unsigned short*)alloc((size_t)(N_NODES + 1) * 64 * 2);
    unsigned short* h1b = (unsigned short*)alloc((size_t)(N_NODES + 1) * 64 * 2);
    unsigned short* h2b = (unsigned short*)alloc((size_t)N_NODES * 64 * 2);
    unsigned short* Wf1 = (unsigned short*)alloc((size_t)512 * 64 * 2);
    unsigned short* Wf2 = (unsigned short*)alloc((size_t)512 * 64 * 2);
    unsigned short* Wsf = (unsigned short*)alloc((size_t)64 * 64 * 2);

    k_init<<<1, 512, 0, stream>>>(cursor);
    k_bscatter<<<(N_EDGES + 4095) / 4096, 1024, 0, stream>>>(ei, ti, cursor, words);
    k_lsort<<<NB, 1024, 0, stream>>>(cursor, words, node_pm, gid_pad);
    k_cvt<<<(N_NODES * 64 + 255) / 256, 256, 0, stream>>>(x, xb, h1b);
    k_wprep<<<(512 * 64 + 255) / 256, 256, 0, stream>>>(W1, W2, Wssl, Wf1, Wf2, Wsf);

    // conv1 fused: agg(xb) + GEMM W1 + relu -> h1b (bf16)
    k_fused<<<N_NODES / 32, 512, 0, stream>>>(node_pm, gid_pad, xb, Wf1, b1, h1b, nullptr);
    // conv2 fused: agg(h1b) + GEMM W2 + relu -> d_out fp32 + h2b bf16
    k_fused<<<N_NODES / 32, 512, 0, stream>>>(node_pm, gid_pad, h1b, Wf2, b2, h2b, out);

    // ssl: h2 @ Wssl + bssl (MFMA)
    k_sslm<<<(NTILES + 3) / 4, 256, 0, stream>>>(h2b, Wsf, bssl, out + (size_t)N_NODES * 64);
}